// Round 16
// baseline (281.175 us; speedup 1.0000x reference)
//
#include <hip/hip_runtime.h>
#include <math.h>

#define Bm 2048
#define Hm 512
#define Em 300
#define Tm 50
#define KWm 812   // H + E
#define KWp 832   // padded to multiple of 32

typedef unsigned short u16;
typedef unsigned int u32;
typedef __attribute__((ext_vector_type(8))) short short8;
typedef __attribute__((ext_vector_type(8))) u16 ushort8v;
typedef __attribute__((ext_vector_type(4))) float f32x4;

__device__ __forceinline__ float sigmoidf_(float x) { return 1.f / (1.f + __expf(-x)); }
// fast tanh: exact at saturation, ~6 VALU ops
__device__ __forceinline__ float tanhfast(float x) { return 1.f - 2.f / (__expf(2.f * x) + 1.f); }

// fp32 -> bf16 bits, round-to-nearest-even
__device__ __forceinline__ u16 bfr(float x) {
    union { float f; u32 u; } c; c.f = x;
    u32 u = c.u;
    u += 0x7FFFu + ((u >> 16) & 1u);
    return (u16)(u >> 16);
}
__device__ __forceinline__ ushort8v cvt8(const float* __restrict__ p) {
    f32x4 v0 = *(const f32x4*)p;
    f32x4 v1 = *(const f32x4*)(p + 4);
    ushort8v r;
    r[0] = bfr(v0[0]); r[1] = bfr(v0[1]); r[2] = bfr(v0[2]); r[3] = bfr(v0[3]);
    r[4] = bfr(v1[0]); r[5] = bfr(v1[1]); r[6] = bfr(v1[2]); r[7] = bfr(v1[3]);
    return r;
}

// async global(bf16,16B) -> LDS, linear dest (wave-uniform base + lane*16)
__device__ __forceinline__ void gload16(const u16* g, u16* l) {
    __builtin_amdgcn_global_load_lds((const __attribute__((address_space(1))) void*)g,
                                     (__attribute__((address_space(3))) void*)l, 16, 0, 0);
}

// ---------------------------------------------------------------------------
// k_prep: ALL prep work in ONE launch so the BW-bound phi conversion overlaps
// the latency-bound qs GEMM and the small packs.
// ---------------------------------------------------------------------------
__global__ __launch_bounds__(256) void k_prep(
        const float* __restrict__ henc, const float* __restrict__ hsum,
        const float* __restrict__ lq, const float* __restrict__ ls,
        const float* __restrict__ Ww, const float* __restrict__ x,
        const float* __restrict__ lkw,
        const float* __restrict__ lqb, const float* __restrict__ lsb,
        const float* __restrict__ lkb, const float* __restrict__ phi,
        u16* __restrict__ Wg, u16* __restrict__ Xb, u16* __restrict__ lkwb,
        float* __restrict__ qbias, u16* __restrict__ phib,
        float* __restrict__ qs) {
    const int job = blockIdx.y;
    const int r = blockIdx.x;
    const int tid = threadIdx.x;
    if (job == 0) {
        for (int c = tid; c < KWp; c += 256)
            Wg[(size_t)r * KWp + c] = (c < KWm) ? bfr(Ww[(size_t)r * KWm + c]) : (u16)0;
    } else if (job == 1) {
        for (int c = 512 + tid; c < KWp; c += 256)
            Xb[(size_t)r * KWp + c] = (c < KWm) ? bfr(x[(size_t)r * Em + (c - 512)]) : (u16)0;
        if (r < 512)
            for (int c = tid; c < 512; c += 256)
                lkwb[(size_t)r * 512 + c] = bfr(lkw[(size_t)r * 512 + c]);
        if (r == 0)
            for (int c = tid; c < 512; c += 256)
                qbias[c] = lqb[c] + lsb[c] + lkb[c];
    } else if (job == 2) {
        const size_t nvec = (size_t)Tm * Bm * 512 / 8;
        for (size_t i = (size_t)r * 256 + tid; i < nvec; i += (size_t)2048 * 256)
            *(ushort8v*)&phib[i * 8] = cvt8(phi + i * 8);
    } else {
        if (r >= 512) return;
        __shared__ u16 Asl[64 * 32];
        __shared__ u16 Bsl[64 * 32];
        const int z = r & 1;
        const int n0 = ((r >> 1) & 7) * 64;
        const int m0 = (r >> 4) * 64;
        const float* A = z ? hsum : henc;
        const float* W = z ? ls : lq;
        const int lane = tid & 63, wid = tid >> 6;
        const int wr = wid >> 1, wc = wid & 1;
        const int l15 = lane & 15, l4 = lane >> 4;
        const int srow = tid >> 2;
        const int gch  = tid & 3;
        const int sslot = gch ^ ((srow >> 1) & 3);
        f32x4 acc[2][2];
        #pragma unroll
        for (int i = 0; i < 2; ++i)
            #pragma unroll
            for (int j = 0; j < 2; ++j) acc[i][j] = (f32x4){0.f, 0.f, 0.f, 0.f};
        for (int k0 = 0; k0 < 512; k0 += 32) {
            __syncthreads();
            *(ushort8v*)&Asl[srow * 32 + sslot * 8] =
                cvt8(A + (size_t)(m0 + srow) * 512 + k0 + gch * 8);
            *(ushort8v*)&Bsl[srow * 32 + sslot * 8] =
                cvt8(W + (size_t)(n0 + srow) * 512 + k0 + gch * 8);
            __syncthreads();
            short8 af[2], bf[2];
            #pragma unroll
            for (int mf = 0; mf < 2; ++mf) {
                int rr = wr * 32 + mf * 16 + l15;
                af[mf] = *(const short8*)&Asl[rr * 32 + (l4 ^ ((rr >> 1) & 3)) * 8];
            }
            #pragma unroll
            for (int nf = 0; nf < 2; ++nf) {
                int rr = wc * 32 + nf * 16 + l15;
                bf[nf] = *(const short8*)&Bsl[rr * 32 + (l4 ^ ((rr >> 1) & 3)) * 8];
            }
            #pragma unroll
            for (int mf = 0; mf < 2; ++mf)
                #pragma unroll
                for (int nf = 0; nf < 2; ++nf)
                    acc[mf][nf] = __builtin_amdgcn_mfma_f32_16x16x32_bf16(
                                      af[mf], bf[nf], acc[mf][nf], 0, 0, 0);
        }
        #pragma unroll
        for (int mf = 0; mf < 2; ++mf)
            #pragma unroll
            for (int nf = 0; nf < 2; ++nf)
                #pragma unroll
                for (int reg = 0; reg < 4; ++reg) {
                    int b = m0 + wr * 32 + mf * 16 + l4 * 4 + reg;
                    int h = n0 + wc * 32 + nf * 16 + l15;
                    atomicAdd(&qs[(size_t)b * Hm + h], acc[mf][nf][reg]);
                }
    }
}

// ---------------------------------------------------------------------------
// k_scores_mfma R16: R15 geometry (BM=256 x BN=128, 512 thr / 8 waves, wave
// tile 64x64) + minimum 2-PHASE PIPELINE: BK=32 double-buffered (2 x 24KB =
// 48KB, same LDS footprint as R15 -> still 2 blocks/CU), STAGE(next tile)
// issued BEFORE the ds_read+MFMA of the current tile, ONE __syncthreads per
// iter (its vmcnt(0) drain is the wait for the stage issued a full MFMA
// phase earlier). Race-safe: barrier at end of iter k-1 ensures all reads
// of buf[cur^1] done before iter k stages into it. 4-chunk XOR involution
// (c ^ ((r>>1)&3), R4/R12-validated 0 conflicts). Per-ks frag loads (32
// VGPR live, no spill). Fused fast-tanh/v_w/row-sum epilogue + atomicAdd,
// XCD-bijective swizzle (1600 = 8x200, n-fastest), setprio around MFMA.
// ---------------------------------------------------------------------------
__global__ __launch_bounds__(512, 4) void k_scores_mfma(
        const u16* __restrict__ phib, const u16* __restrict__ lkwb,
        const float* __restrict__ qs2, const float* __restrict__ vw,
        const float* __restrict__ qbias, float* __restrict__ scores) {
    __shared__ u16 Asl[2][256 * 32];   // 2 x 16 KB
    __shared__ u16 Bsl[2][128 * 32];   // 2 x  8 KB
    const int d  = blockIdx.x;
    const int wg = (d & 7) * 200 + (d >> 3);   // bijective: 1600 = 8*200
    const int n0 = (wg & 3) << 7;              // 4 n-tiles of 128, fastest
    const int m0 = (wg >> 2) << 8;             // 400 m-tiles of 256
    const int t  = m0 >> 11;                   // 256 | 2048
    const int b0 = m0 & (Bm - 1);
    const int tid = threadIdx.x, lane = tid & 63, wid = tid >> 6;
    const int wm = wid >> 1, wn = wid & 1;     // 4m x 2n wave grid
    const int l15 = lane & 15, l4 = lane >> 4;
    const int srw = lane >> 2;                 // 0..15 row-in-group (staging)
    const int sch = lane & 3;                  // chunk slot 0..3

    f32x4 acc[4][4];
    #pragma unroll
    for (int i = 0; i < 4; ++i)
        #pragma unroll
        for (int j = 0; j < 4; ++j) acc[i][j] = (f32x4){0.f, 0.f, 0.f, 0.f};

    // stage one BK=32 K-tile into buffer `buf` (A: 2 instrs, B: 1 instr)
    auto STAGE = [&](int buf, int kt) {
        const int k0 = kt << 5;
        #pragma unroll
        for (int j = 0; j < 2; ++j) {
            int r = (wid << 5) + (j << 4) + srw;           // A rows 0..255
            int gc = sch ^ ((r >> 1) & 3);
            gload16(phib + (size_t)(m0 + r) * 512 + k0 + gc * 8,
                    &Asl[buf][((wid << 5) + (j << 4)) * 32]);
        }
        {
            int r = (wid << 4) + srw;                      // B rows 0..127
            int gc = sch ^ ((r >> 1) & 3);
            gload16(lkwb + (size_t)(n0 + r) * 512 + k0 + gc * 8,
                    &Bsl[buf][(wid << 4) * 32]);
        }
    };

    STAGE(0, 0);
    __syncthreads();                   // tile 0 landed
    int cur = 0;
    #pragma unroll 1
    for (int kt = 0; kt < 16; ++kt) {
        if (kt < 15) STAGE(cur ^ 1, kt + 1);   // overlap with this iter's MFMA
        short8 af[4], bf[4];
        #pragma unroll
        for (int mf = 0; mf < 4; ++mf) {
            int r = wm * 64 + mf * 16 + l15;
            af[mf] = *(const short8*)&Asl[cur][r * 32 + (l4 ^ ((r >> 1) & 3)) * 8];
        }
        #pragma unroll
        for (int nf = 0; nf < 4; ++nf) {
            int r = wn * 64 + nf * 16 + l15;
            bf[nf] = *(const short8*)&Bsl[cur][r * 32 + (l4 ^ ((r >> 1) & 3)) * 8];
        }
        __builtin_amdgcn_s_setprio(1);
        #pragma unroll
        for (int mf = 0; mf < 4; ++mf)
            #pragma unroll
            for (int nf = 0; nf < 4; ++nf)
                acc[mf][nf] = __builtin_amdgcn_mfma_f32_16x16x32_bf16(
                                  af[mf], bf[nf], acc[mf][nf], 0, 0, 0);
        __builtin_amdgcn_s_setprio(0);
        __syncthreads();               // drains stage (next tile) + reads done
        cur ^= 1;
    }

    // epilogue: fast tanh + v_w dot + row-sum, one atomicAdd per row per wave
    float vws[4], qb[4];
    int av[4];
    #pragma unroll
    for (int nf = 0; nf < 4; ++nf) {
        av[nf] = n0 + wn * 64 + nf * 16 + l15;
        vws[nf] = vw[av[nf]];
        qb[nf]  = qbias[av[nf]];
    }
    #pragma unroll
    for (int mf = 0; mf < 4; ++mf) {
        #pragma unroll
        for (int reg = 0; reg < 4; ++reg) {
            int b = b0 + wm * 64 + mf * 16 + l4 * 4 + reg;
            const float* q = qs2 + (size_t)b * Hm;
            float s = 0.f;
            #pragma unroll
            for (int nf = 0; nf < 4; ++nf)
                s = fmaf(tanhfast(acc[mf][nf][reg] + q[av[nf]] + qb[nf]), vws[nf], s);
            #pragma unroll
            for (int o = 1; o < 16; o <<= 1) s += __shfl_xor(s, o);
            if (l15 == 0) atomicAdd(&scores[(size_t)b * Tm + t], s);
        }
    }
}

// ---------------------------------------------------------------------------
// k_attn: softmax over T, weighted sums over bf16 phi + fp32 cell.
// ---------------------------------------------------------------------------
__global__ __launch_bounds__(256) void k_attn(
        const u16* __restrict__ phib, const float* __restrict__ cell,
        const float* __restrict__ scores,
        u16* __restrict__ Xb, float* __restrict__ cs) {
    __shared__ float p[Tm];
    const int b = blockIdx.x;
    const int tid = threadIdx.x;
    if (tid < 64) {
        float s = (tid < Tm) ? scores[(size_t)b * Tm + tid] : -INFINITY;
        float m = s;
        #pragma unroll
        for (int o = 32; o; o >>= 1) m = fmaxf(m, __shfl_xor(m, o));
        float ex = (tid < Tm) ? __expf(s - m) : 0.f;
        float sum = ex;
        #pragma unroll
        for (int o = 32; o; o >>= 1) sum += __shfl_xor(sum, o);
        if (tid < Tm) p[tid] = ex / sum;
    }
    __syncthreads();
    const int c0 = tid * 2;
    float ah0 = 0.f, ah1 = 0.f, ac0 = 0.f, ac1 = 0.f;
    for (int t = 0; t < Tm; ++t) {
        float w = p[t];
        const size_t rb = ((size_t)t * Bm + b) * 512 + c0;
        u32 ph2 = *(const u32*)&phib[rb];
        float2 ce2 = *(const float2*)&cell[rb];
        float p0 = __uint_as_float(ph2 << 16);
        float p1 = __uint_as_float(ph2 & 0xFFFF0000u);
        ah0 = fmaf(w, p0, ah0);
        ah1 = fmaf(w, p1, ah1);
        ac0 = fmaf(w, ce2.x, ac0);
        ac1 = fmaf(w, ce2.y, ac1);
    }
    *(u32*)&Xb[(size_t)b * KWp + c0] = (u32)bfr(ah0) | ((u32)bfr(ah1) << 16);
    *(float2*)&cs[(size_t)b * Hm + c0] = make_float2(ac0, ac1);
}

// ---------------------------------------------------------------------------
// k_gates_mfma: gates = Xb(2048x832) @ Wg^T(2048x832), bf16 MFMA.
// BK=64 -> 13 K-iters, R7 stage/read swizzle, XCD-bijective block swizzle.
// ---------------------------------------------------------------------------
__global__ __launch_bounds__(256) void k_gates_mfma(
        const u16* __restrict__ Xb, const u16* __restrict__ Wg,
        float* __restrict__ gates) {
    __shared__ u16 Asl[64 * 64];
    __shared__ u16 Bsl[128 * 64];
    const int d  = blockIdx.x;
    const int wg = (d & 7) * 64 + (d >> 3);
    const int m0 = (wg & 31) << 6;
    const int n0 = (wg >> 5) << 7;
    const int tid = threadIdx.x, lane = tid & 63, wid = tid >> 6;
    const int wr = wid >> 1, wc = wid & 1;
    const int l15 = lane & 15, l4 = lane >> 4;
    const int rin = lane >> 3;
    const int schunk = (lane & 7) ^ rin;
    f32x4 acc[2][4];
    #pragma unroll
    for (int i = 0; i < 2; ++i)
        #pragma unroll
        for (int j = 0; j < 4; ++j) acc[i][j] = (f32x4){0.f, 0.f, 0.f, 0.f};

    for (int kt = 0; kt < 13; ++kt) {
        const int k0 = kt << 6;
        __syncthreads();
        #pragma unroll
        for (int j = 0; j < 2; ++j) {
            int r = (wid << 4) + (j << 3) + rin;
            gload16(Xb + (size_t)(m0 + r) * KWp + k0 + schunk * 8,
                    &Asl[((wid << 4) + (j << 3)) * 64]);
        }
        #pragma unroll
        for (int j = 0; j < 4; ++j) {
            int r = (wid << 5) + (j << 3) + rin;
            gload16(Wg + (size_t)(n0 + r) * KWp + k0 + schunk * 8,
                    &Bsl[((wid << 5) + (j << 3)) * 64]);
        }
        __syncthreads();
        short8 af[2][2], bf[4][2];
        #pragma unroll
        for (int mf = 0; mf < 2; ++mf) {
            int r = wr * 32 + mf * 16 + l15;
            #pragma unroll
            for (int ks = 0; ks < 2; ++ks) {
                int c = ks * 4 + l4;
                af[mf][ks] = *(const short8*)&Asl[r * 64 + (c ^ (r & 7)) * 8];
            }
        }
        #pragma unroll
        for (int nf = 0; nf < 4; ++nf) {
            int r = wc * 64 + nf * 16 + l15;
            #pragma unroll
            for (int ks = 0; ks < 2; ++ks) {
                int c = ks * 4 + l4;
                bf[nf][ks] = *(const short8*)&Bsl[r * 64 + (c ^ (r & 7)) * 8];
            }
        }
        __builtin_amdgcn_s_setprio(1);
        #pragma unroll
        for (int ks = 0; ks < 2; ++ks)
            #pragma unroll
            for (int mf = 0; mf < 2; ++mf)
                #pragma unroll
                for (int nf = 0; nf < 4; ++nf)
                    acc[mf][nf] = __builtin_amdgcn_mfma_f32_16x16x32_bf16(
                                      af[mf][ks], bf[nf][ks], acc[mf][nf], 0, 0, 0);
        __builtin_amdgcn_s_setprio(0);
    }
    #pragma unroll
    for (int mf = 0; mf < 2; ++mf)
        #pragma unroll
        for (int nf = 0; nf < 4; ++nf)
            #pragma unroll
            for (int reg = 0; reg < 4; ++reg) {
                int b = m0 + wr * 32 + mf * 16 + l4 * 4 + reg;
                int n = n0 + wc * 64 + nf * 16 + l15;
                gates[(size_t)b * 2048 + n] = acc[mf][nf][reg];
            }
}

// ---------------------------------------------------------------------------
// k_lstm: elementwise LSTM epilogue over [B,H].
// ---------------------------------------------------------------------------
__global__ __launch_bounds__(256) void k_lstm(
        const float* __restrict__ gates, const float* __restrict__ Wb,
        const float* __restrict__ cs, float* __restrict__ out) {
    const int idx = blockIdx.x * 256 + threadIdx.x;
    const int b = idx >> 9, h = idx & 511;
    const float* g = gates + (size_t)b * 2048;
    float f  = sigmoidf_(g[h]        + Wb[h]);
    float o  = sigmoidf_(g[512 + h]  + Wb[512 + h]);
    float ii = sigmoidf_(g[1024 + h] + Wb[1024 + h]);
    float ch = tanhfast( g[1536 + h] + Wb[1536 + h]);
    float c  = f * cs[idx] + ii * ch;
    out[idx] = o * tanhfast(c);
}

extern "C" void kernel_launch(void* const* d_in, const int* in_sizes, int n_in,
                              void* d_out, int out_size, void* d_ws, size_t ws_size,
                              hipStream_t stream) {
    const float* x      = (const float*)d_in[0];
    const float* h_enc  = (const float*)d_in[1];
    const float* phi    = (const float*)d_in[2];
    const float* cell   = (const float*)d_in[3];
    const float* h_summ = (const float*)d_in[4];
    // d_in[5] c_summ: unused by the reference
    const float* W_w    = (const float*)d_in[6];
    const float* W_b    = (const float*)d_in[7];
    const float* v_w    = (const float*)d_in[8];
    // d_in[9] v_b: softmax-invariant, dropped
    const float* lq_w   = (const float*)d_in[10];
    const float* lq_b   = (const float*)d_in[11];
    const float* lk_w   = (const float*)d_in[12];
    const float* lk_b   = (const float*)d_in[13];
    const float* ls_w   = (const float*)d_in[14];
    const float* ls_b   = (const float*)d_in[15];
    float* out = (float*)d_out;

    char* w = (char*)d_ws;
    // phib: 0 .. 104,857,600 (52.4M bf16). gates (16.78 MB) ALIASES phib:
    // phib's last reader (k_attn) finishes before k_gates_mfma writes gates.
    u16*   phib   = (u16*)  (w);
    float* gates  = (float*)(w);
    float* qs     = (float*)(w + 104857600);                // 4.00 MB
    float* scores = (float*)(w + 109051904);                // 0.40 MB (adjacent to qs)
    float* cs     = (float*)(w + 109461504);                // 4.00 MB
    u16*   Wg     = (u16*)  (w + 113655808);                // 3.41 MB
    u16*   Xb     = (u16*)  (w + 117063680);                // 3.41 MB
    u16*   lkwb   = (u16*)  (w + 120471552);                // 0.52 MB
    float* qbias  = (float*)(w + 121520128);                // 2 KB (end ~121.6 MB)

    // one memset covers qs (4MB) + adjacent scores (0.4MB)
    hipMemsetAsync(qs, 0, 4194304 + (size_t)Bm * Tm * sizeof(float), stream);
    k_prep<<<dim3(2048, 4), 256, 0, stream>>>(h_enc, h_summ, lq_w, ls_w, W_w, x, lk_w,
                                              lq_b, ls_b, lk_b, phi,
                                              Wg, Xb, lkwb, qbias, phib, qs);
    k_scores_mfma<<<dim3(1600), 512, 0, stream>>>(phib, lkwb, qs, v_w, qbias, scores);
    k_attn<<<dim3(Bm), 256, 0, stream>>>(phib, cell, scores, Xb, cs);
    k_gates_mfma<<<dim3(512), 256, 0, stream>>>(Xb, Wg, gates);
    k_lstm<<<dim3((Bm * Hm) / 256), 256, 0, stream>>>(gates, W_b, cs, out);
}

// Round 17
// 270.957 us; speedup vs baseline: 1.0377x; 1.0377x over previous
//
#include <hip/hip_runtime.h>
#include <math.h>

#define Bm 2048
#define Hm 512
#define Em 300
#define Tm 50
#define KWm 812   // H + E
#define KWp 832   // padded to multiple of 32

typedef unsigned short u16;
typedef unsigned int u32;
typedef __attribute__((ext_vector_type(8))) short short8;
typedef __attribute__((ext_vector_type(8))) u16 ushort8v;
typedef __attribute__((ext_vector_type(4))) float f32x4;

__device__ __forceinline__ float sigmoidf_(float x) { return 1.f / (1.f + __expf(-x)); }
// fast tanh: exact at saturation, ~6 VALU ops
__device__ __forceinline__ float tanhfast(float x) { return 1.f - 2.f / (__expf(2.f * x) + 1.f); }

// fp32 -> bf16 bits, round-to-nearest-even
__device__ __forceinline__ u16 bfr(float x) {
    union { float f; u32 u; } c; c.f = x;
    u32 u = c.u;
    u += 0x7FFFu + ((u >> 16) & 1u);
    return (u16)(u >> 16);
}
__device__ __forceinline__ ushort8v cvt8(const float* __restrict__ p) {
    f32x4 v0 = *(const f32x4*)p;
    f32x4 v1 = *(const f32x4*)(p + 4);
    ushort8v r;
    r[0] = bfr(v0[0]); r[1] = bfr(v0[1]); r[2] = bfr(v0[2]); r[3] = bfr(v0[3]);
    r[4] = bfr(v1[0]); r[5] = bfr(v1[1]); r[6] = bfr(v1[2]); r[7] = bfr(v1[3]);
    return r;
}

// async global(bf16,16B) -> LDS, linear dest (wave-uniform base + lane*16)
__device__ __forceinline__ void gload16(const u16* g, u16* l) {
    __builtin_amdgcn_global_load_lds((const __attribute__((address_space(1))) void*)g,
                                     (__attribute__((address_space(3))) void*)l, 16, 0, 0);
}

// ---------------------------------------------------------------------------
// k_prep: ALL prep work in ONE launch so the BW-bound phi conversion overlaps
// the latency-bound qs GEMM and the small packs.
// ---------------------------------------------------------------------------
__global__ __launch_bounds__(256) void k_prep(
        const float* __restrict__ henc, const float* __restrict__ hsum,
        const float* __restrict__ lq, const float* __restrict__ ls,
        const float* __restrict__ Ww, const float* __restrict__ x,
        const float* __restrict__ lkw,
        const float* __restrict__ lqb, const float* __restrict__ lsb,
        const float* __restrict__ lkb, const float* __restrict__ phi,
        u16* __restrict__ Wg, u16* __restrict__ Xb, u16* __restrict__ lkwb,
        float* __restrict__ qbias, u16* __restrict__ phib,
        float* __restrict__ qs) {
    const int job = blockIdx.y;
    const int r = blockIdx.x;
    const int tid = threadIdx.x;
    if (job == 0) {
        for (int c = tid; c < KWp; c += 256)
            Wg[(size_t)r * KWp + c] = (c < KWm) ? bfr(Ww[(size_t)r * KWm + c]) : (u16)0;
    } else if (job == 1) {
        for (int c = 512 + tid; c < KWp; c += 256)
            Xb[(size_t)r * KWp + c] = (c < KWm) ? bfr(x[(size_t)r * Em + (c - 512)]) : (u16)0;
        if (r < 512)
            for (int c = tid; c < 512; c += 256)
                lkwb[(size_t)r * 512 + c] = bfr(lkw[(size_t)r * 512 + c]);
        if (r == 0)
            for (int c = tid; c < 512; c += 256)
                qbias[c] = lqb[c] + lsb[c] + lkb[c];
    } else if (job == 2) {
        const size_t nvec = (size_t)Tm * Bm * 512 / 8;
        for (size_t i = (size_t)r * 256 + tid; i < nvec; i += (size_t)2048 * 256)
            *(ushort8v*)&phib[i * 8] = cvt8(phi + i * 8);
    } else {
        if (r >= 512) return;
        __shared__ u16 Asl[64 * 32];
        __shared__ u16 Bsl[64 * 32];
        const int z = r & 1;
        const int n0 = ((r >> 1) & 7) * 64;
        const int m0 = (r >> 4) * 64;
        const float* A = z ? hsum : henc;
        const float* W = z ? ls : lq;
        const int lane = tid & 63, wid = tid >> 6;
        const int wr = wid >> 1, wc = wid & 1;
        const int l15 = lane & 15, l4 = lane >> 4;
        const int srow = tid >> 2;
        const int gch  = tid & 3;
        const int sslot = gch ^ ((srow >> 1) & 3);
        f32x4 acc[2][2];
        #pragma unroll
        for (int i = 0; i < 2; ++i)
            #pragma unroll
            for (int j = 0; j < 2; ++j) acc[i][j] = (f32x4){0.f, 0.f, 0.f, 0.f};
        for (int k0 = 0; k0 < 512; k0 += 32) {
            __syncthreads();
            *(ushort8v*)&Asl[srow * 32 + sslot * 8] =
                cvt8(A + (size_t)(m0 + srow) * 512 + k0 + gch * 8);
            *(ushort8v*)&Bsl[srow * 32 + sslot * 8] =
                cvt8(W + (size_t)(n0 + srow) * 512 + k0 + gch * 8);
            __syncthreads();
            short8 af[2], bf[2];
            #pragma unroll
            for (int mf = 0; mf < 2; ++mf) {
                int rr = wr * 32 + mf * 16 + l15;
                af[mf] = *(const short8*)&Asl[rr * 32 + (l4 ^ ((rr >> 1) & 3)) * 8];
            }
            #pragma unroll
            for (int nf = 0; nf < 2; ++nf) {
                int rr = wc * 32 + nf * 16 + l15;
                bf[nf] = *(const short8*)&Bsl[rr * 32 + (l4 ^ ((rr >> 1) & 3)) * 8];
            }
            #pragma unroll
            for (int mf = 0; mf < 2; ++mf)
                #pragma unroll
                for (int nf = 0; nf < 2; ++nf)
                    acc[mf][nf] = __builtin_amdgcn_mfma_f32_16x16x32_bf16(
                                      af[mf], bf[nf], acc[mf][nf], 0, 0, 0);
        }
        #pragma unroll
        for (int mf = 0; mf < 2; ++mf)
            #pragma unroll
            for (int nf = 0; nf < 2; ++nf)
                #pragma unroll
                for (int reg = 0; reg < 4; ++reg) {
                    int b = m0 + wr * 32 + mf * 16 + l4 * 4 + reg;
                    int h = n0 + wc * 32 + nf * 16 + l15;
                    atomicAdd(&qs[(size_t)b * Hm + h], acc[mf][nf][reg]);
                }
    }
}

// ---------------------------------------------------------------------------
// k_scores_mfma (R15 exact — session best, 128-130us / 416 TF):
// BM=256 x BN=128, 512 thr / 8 waves (4m x 2n), wave tile 64x64, BK=64,
// single-buffered 48KB LDS, drain __syncthreads. Per-ks frag loads (32 VGPR
// live -> no spill under the (512,4) cap; 2 blocks/CU = 16 waves/CU).
// Stage/read XOR involution (chunk ^ row&7), XCD-bijective swizzle
// (1600 = 8x200, n-fastest -> FETCH at the 112MB ideal), setprio around
// MFMA, fused fast-tanh/v_w/row-sum epilogue + atomicAdd into scores.
// ---------------------------------------------------------------------------
__global__ __launch_bounds__(512, 4) void k_scores_mfma(
        const u16* __restrict__ phib, const u16* __restrict__ lkwb,
        const float* __restrict__ qs2, const float* __restrict__ vw,
        const float* __restrict__ qbias, float* __restrict__ scores) {
    __shared__ u16 Asl[256 * 64];      // 32 KB
    __shared__ u16 Bsl[128 * 64];      // 16 KB
    const int d  = blockIdx.x;
    const int wg = (d & 7) * 200 + (d >> 3);   // bijective: 1600 = 8*200
    const int n0 = (wg & 3) << 7;              // 4 n-tiles of 128, fastest
    const int m0 = (wg >> 2) << 8;             // 400 m-tiles of 256
    const int t  = m0 >> 11;                   // 256 | 2048
    const int b0 = m0 & (Bm - 1);
    const int tid = threadIdx.x, lane = tid & 63, wid = tid >> 6;
    const int wm = wid >> 1, wn = wid & 1;     // 4m x 2n wave grid
    const int l15 = lane & 15, l4 = lane >> 4;
    const int rin = lane >> 3;                 // 0..7 row-in-group
    const int schunk = (lane & 7) ^ rin;       // inverse-swizzled source chunk

    f32x4 acc[4][4];
    #pragma unroll
    for (int i = 0; i < 4; ++i)
        #pragma unroll
        for (int j = 0; j < 4; ++j) acc[i][j] = (f32x4){0.f, 0.f, 0.f, 0.f};

    for (int kt = 0; kt < 8; ++kt) {
        const int k0 = kt << 6;
        __syncthreads();   // previous iter's reads complete
        // A: 256 rows, 4 instrs/thread
        #pragma unroll
        for (int j = 0; j < 4; ++j) {
            int r = (wid << 5) + (j << 3) + rin;
            gload16(phib + (size_t)(m0 + r) * 512 + k0 + schunk * 8,
                    &Asl[((wid << 5) + (j << 3)) * 64]);
        }
        // B: 128 rows, 2 instrs/thread
        #pragma unroll
        for (int j = 0; j < 2; ++j) {
            int r = (wid << 4) + (j << 3) + rin;
            gload16(lkwb + (size_t)(n0 + r) * 512 + k0 + schunk * 8,
                    &Bsl[((wid << 4) + (j << 3)) * 64]);
        }
        __syncthreads();   // drains vmcnt -> tile visible to all waves
        __builtin_amdgcn_s_setprio(1);
        #pragma unroll
        for (int ks = 0; ks < 2; ++ks) {       // per-ks frags: 32 VGPR live
            short8 af[4], bf[4];
            const int c = ks * 4 + l4;
            #pragma unroll
            for (int mf = 0; mf < 4; ++mf) {
                int r = wm * 64 + mf * 16 + l15;
                af[mf] = *(const short8*)&Asl[r * 64 + (c ^ (r & 7)) * 8];
            }
            #pragma unroll
            for (int nf = 0; nf < 4; ++nf) {
                int r = wn * 64 + nf * 16 + l15;
                bf[nf] = *(const short8*)&Bsl[r * 64 + (c ^ (r & 7)) * 8];
            }
            #pragma unroll
            for (int mf = 0; mf < 4; ++mf)
                #pragma unroll
                for (int nf = 0; nf < 4; ++nf)
                    acc[mf][nf] = __builtin_amdgcn_mfma_f32_16x16x32_bf16(
                                      af[mf], bf[nf], acc[mf][nf], 0, 0, 0);
        }
        __builtin_amdgcn_s_setprio(0);
    }

    // epilogue: fast tanh + v_w dot + row-sum, one atomicAdd per row per wave
    float vws[4], qb[4];
    int av[4];
    #pragma unroll
    for (int nf = 0; nf < 4; ++nf) {
        av[nf] = n0 + wn * 64 + nf * 16 + l15;
        vws[nf] = vw[av[nf]];
        qb[nf]  = qbias[av[nf]];
    }
    #pragma unroll
    for (int mf = 0; mf < 4; ++mf) {
        #pragma unroll
        for (int reg = 0; reg < 4; ++reg) {
            int b = b0 + wm * 64 + mf * 16 + l4 * 4 + reg;
            const float* q = qs2 + (size_t)b * Hm;
            float s = 0.f;
            #pragma unroll
            for (int nf = 0; nf < 4; ++nf)
                s = fmaf(tanhfast(acc[mf][nf][reg] + q[av[nf]] + qb[nf]), vws[nf], s);
            #pragma unroll
            for (int o = 1; o < 16; o <<= 1) s += __shfl_xor(s, o);
            if (l15 == 0) atomicAdd(&scores[(size_t)b * Tm + t], s);
        }
    }
}

// ---------------------------------------------------------------------------
// k_attn: softmax over T, weighted sums over bf16 phi + fp32 cell.
// ---------------------------------------------------------------------------
__global__ __launch_bounds__(256) void k_attn(
        const u16* __restrict__ phib, const float* __restrict__ cell,
        const float* __restrict__ scores,
        u16* __restrict__ Xb, float* __restrict__ cs) {
    __shared__ float p[Tm];
    const int b = blockIdx.x;
    const int tid = threadIdx.x;
    if (tid < 64) {
        float s = (tid < Tm) ? scores[(size_t)b * Tm + tid] : -INFINITY;
        float m = s;
        #pragma unroll
        for (int o = 32; o; o >>= 1) m = fmaxf(m, __shfl_xor(m, o));
        float ex = (tid < Tm) ? __expf(s - m) : 0.f;
        float sum = ex;
        #pragma unroll
        for (int o = 32; o; o >>= 1) sum += __shfl_xor(sum, o);
        if (tid < Tm) p[tid] = ex / sum;
    }
    __syncthreads();
    const int c0 = tid * 2;
    float ah0 = 0.f, ah1 = 0.f, ac0 = 0.f, ac1 = 0.f;
    for (int t = 0; t < Tm; ++t) {
        float w = p[t];
        const size_t rb = ((size_t)t * Bm + b) * 512 + c0;
        u32 ph2 = *(const u32*)&phib[rb];
        float2 ce2 = *(const float2*)&cell[rb];
        float p0 = __uint_as_float(ph2 << 16);
        float p1 = __uint_as_float(ph2 & 0xFFFF0000u);
        ah0 = fmaf(w, p0, ah0);
        ah1 = fmaf(w, p1, ah1);
        ac0 = fmaf(w, ce2.x, ac0);
        ac1 = fmaf(w, ce2.y, ac1);
    }
    *(u32*)&Xb[(size_t)b * KWp + c0] = (u32)bfr(ah0) | ((u32)bfr(ah1) << 16);
    *(float2*)&cs[(size_t)b * Hm + c0] = make_float2(ac0, ac1);
}

// ---------------------------------------------------------------------------
// k_gates_mfma: gates = Xb(2048x832) @ Wg^T(2048x832), bf16 MFMA.
// BK=64 -> 13 K-iters, R7 stage/read swizzle, XCD-bijective block swizzle.
// ---------------------------------------------------------------------------
__global__ __launch_bounds__(256) void k_gates_mfma(
        const u16* __restrict__ Xb, const u16* __restrict__ Wg,
        float* __restrict__ gates) {
    __shared__ u16 Asl[64 * 64];
    __shared__ u16 Bsl[128 * 64];
    const int d  = blockIdx.x;
    const int wg = (d & 7) * 64 + (d >> 3);
    const int m0 = (wg & 31) << 6;
    const int n0 = (wg >> 5) << 7;
    const int tid = threadIdx.x, lane = tid & 63, wid = tid >> 6;
    const int wr = wid >> 1, wc = wid & 1;
    const int l15 = lane & 15, l4 = lane >> 4;
    const int rin = lane >> 3;
    const int schunk = (lane & 7) ^ rin;
    f32x4 acc[2][4];
    #pragma unroll
    for (int i = 0; i < 2; ++i)
        #pragma unroll
        for (int j = 0; j < 4; ++j) acc[i][j] = (f32x4){0.f, 0.f, 0.f, 0.f};

    for (int kt = 0; kt < 13; ++kt) {
        const int k0 = kt << 6;
        __syncthreads();
        #pragma unroll
        for (int j = 0; j < 2; ++j) {
            int r = (wid << 4) + (j << 3) + rin;
            gload16(Xb + (size_t)(m0 + r) * KWp + k0 + schunk * 8,
                    &Asl[((wid << 4) + (j << 3)) * 64]);
        }
        #pragma unroll
        for (int j = 0; j < 4; ++j) {
            int r = (wid << 5) + (j << 3) + rin;
            gload16(Wg + (size_t)(n0 + r) * KWp + k0 + schunk * 8,
                    &Bsl[((wid << 5) + (j << 3)) * 64]);
        }
        __syncthreads();
        short8 af[2][2], bf[4][2];
        #pragma unroll
        for (int mf = 0; mf < 2; ++mf) {
            int r = wr * 32 + mf * 16 + l15;
            #pragma unroll
            for (int ks = 0; ks < 2; ++ks) {
                int c = ks * 4 + l4;
                af[mf][ks] = *(const short8*)&Asl[r * 64 + (c ^ (r & 7)) * 8];
            }
        }
        #pragma unroll
        for (int nf = 0; nf < 4; ++nf) {
            int r = wc * 64 + nf * 16 + l15;
            #pragma unroll
            for (int ks = 0; ks < 2; ++ks) {
                int c = ks * 4 + l4;
                bf[nf][ks] = *(const short8*)&Bsl[r * 64 + (c ^ (r & 7)) * 8];
            }
        }
        __builtin_amdgcn_s_setprio(1);
        #pragma unroll
        for (int ks = 0; ks < 2; ++ks)
            #pragma unroll
            for (int mf = 0; mf < 2; ++mf)
                #pragma unroll
                for (int nf = 0; nf < 4; ++nf)
                    acc[mf][nf] = __builtin_amdgcn_mfma_f32_16x16x32_bf16(
                                      af[mf][ks], bf[nf][ks], acc[mf][nf], 0, 0, 0);
        __builtin_amdgcn_s_setprio(0);
    }
    #pragma unroll
    for (int mf = 0; mf < 2; ++mf)
        #pragma unroll
        for (int nf = 0; nf < 4; ++nf)
            #pragma unroll
            for (int reg = 0; reg < 4; ++reg) {
                int b = m0 + wr * 32 + mf * 16 + l4 * 4 + reg;
                int n = n0 + wc * 64 + nf * 16 + l15;
                gates[(size_t)b * 2048 + n] = acc[mf][nf][reg];
            }
}

// ---------------------------------------------------------------------------
// k_lstm: elementwise LSTM epilogue over [B,H].
// ---------------------------------------------------------------------------
__global__ __launch_bounds__(256) void k_lstm(
        const float* __restrict__ gates, const float* __restrict__ Wb,
        const float* __restrict__ cs, float* __restrict__ out) {
    const int idx = blockIdx.x * 256 + threadIdx.x;
    const int b = idx >> 9, h = idx & 511;
    const float* g = gates + (size_t)b * 2048;
    float f  = sigmoidf_(g[h]        + Wb[h]);
    float o  = sigmoidf_(g[512 + h]  + Wb[512 + h]);
    float ii = sigmoidf_(g[1024 + h] + Wb[1024 + h]);
    float ch = tanhfast( g[1536 + h] + Wb[1536 + h]);
    float c  = f * cs[idx] + ii * ch;
    out[idx] = o * tanhfast(c);
}

extern "C" void kernel_launch(void* const* d_in, const int* in_sizes, int n_in,
                              void* d_out, int out_size, void* d_ws, size_t ws_size,
                              hipStream_t stream) {
    const float* x      = (const float*)d_in[0];
    const float* h_enc  = (const float*)d_in[1];
    const float* phi    = (const float*)d_in[2];
    const float* cell   = (const float*)d_in[3];
    const float* h_summ = (const float*)d_in[4];
    // d_in[5] c_summ: unused by the reference
    const float* W_w    = (const float*)d_in[6];
    const float* W_b    = (const float*)d_in[7];
    const float* v_w    = (const float*)d_in[8];
    // d_in[9] v_b: softmax-invariant, dropped
    const float* lq_w   = (const float*)d_in[10];
    const float* lq_b   = (const float*)d_in[11];
    const float* lk_w   = (const float*)d_in[12];
    const float* lk_b   = (const float*)d_in[13];
    const float* ls_w   = (const float*)d_in[14];
    const float* ls_b   = (const float*)d_in[15];
    float* out = (float*)d_out;

    char* w = (char*)d_ws;
    // phib: 0 .. 104,857,600 (52.4M bf16). gates (16.78 MB) ALIASES phib:
    // phib's last reader (k_attn) finishes before k_gates_mfma writes gates.
    u16*   phib   = (u16*)  (w);
    float* gates  = (float*)(w);
    float* qs     = (float*)(w + 104857600);                // 4.00 MB
    float* scores = (float*)(w + 109051904);                // 0.40 MB (adjacent to qs)
    float* cs     = (float*)(w + 109461504);                // 4.00 MB
    u16*   Wg     = (u16*)  (w + 113655808);                // 3.41 MB
    u16*   Xb     = (u16*)  (w + 117063680);                // 3.41 MB
    u16*   lkwb   = (u16*)  (w + 120471552);                // 0.52 MB
    float* qbias  = (float*)(w + 121520128);                // 2 KB (end ~121.6 MB)

    // one memset covers qs (4MB) + adjacent scores (0.4MB)
    hipMemsetAsync(qs, 0, 4194304 + (size_t)Bm * Tm * sizeof(float), stream);
    k_prep<<<dim3(2048, 4), 256, 0, stream>>>(h_enc, h_summ, lq_w, ls_w, W_w, x, lk_w,
                                              lq_b, ls_b, lk_b, phi,
                                              Wg, Xb, lkwb, qbias, phib, qs);
    k_scores_mfma<<<dim3(1600), 512, 0, stream>>>(phib, lkwb, qs, v_w, qbias, scores);
    k_attn<<<dim3(Bm), 256, 0, stream>>>(phib, cell, scores, Xb, cs);
    k_gates_mfma<<<dim3(512), 256, 0, stream>>>(Xb, Wg, gates);
    k_lstm<<<dim3((Bm * Hm) / 256), 256, 0, stream>>>(gates, W_b, cs, out);
}